// Round 13
// baseline (496.351 us; speedup 1.0000x reference)
//
#include <hip/hip_runtime.h>
#include <hip/hip_bf16.h>
#include <hip/hip_cooperative_groups.h>

namespace cg = cooperative_groups;

#define NN   2048
#define DDIM 128
#define HH    8
#define DHH  16
#define NEDGE 65536
#define FFN  512
#define EPSV 1e-5f
#define CAP  256
#define SCP  9   // padded stride for sc[] (coprime with 32 banks)

typedef const float* fp_c;

struct Params {
    const float *node, *edge_feat;
    const int *src, *dst;
    const float *Wq, *bq, *Wk, *bk, *Wv, *bv, *Wo, *bo, *We, *be;
    float *Qf, *Kf, *Vf, *attn_o;
    int* eid;
    unsigned* bm;
    float* eb;
};

__device__ __forceinline__ bool idx64(const int* src) {
    return (src[1] | src[3] | src[5] | src[7] | src[9] | src[11]) == 0;
}

union SmemU {
    struct { float sx[4][DDIM]; } q;                                   // 2 KB
    struct { float qrow[DDIM]; int lj[CAP + 8]; int lev[CAP + 8];
             float sc[CAP + 8][SCP]; float hinv[HH];
             float redpv[2][DDIM]; int scnt; } a;                      // ~13.3 KB
};

// ---- phase bodies (shared by coop kernel and fallback kernels) ----

// prep slice: eid streaming clear (-2), bm clear, edge-bias GEMM. g in [0, 524288).
__device__ __forceinline__ void body_prep(const Params& P, int g) {
    int4 m2 = make_int4(-2, -2, -2, -2);
    ((int4*)P.eid)[g] = m2;
    ((int4*)P.eid)[g + 524288] = m2;
    if (g < NN * 64 / 4) ((int4*)P.bm)[g] = make_int4(0, 0, 0, 0);
    if (g < NEDGE) {
        float ef[10];
#pragma unroll
        for (int k = 0; k < 10; k++) ef[k] = P.edge_feat[g * 10 + k];
#pragma unroll
        for (int h = 0; h < 8; h++) {
            float a = P.be[h];
#pragma unroll
            for (int k = 0; k < 10; k++) a += ef[k] * P.We[k * 8 + h];
            P.eb[g * 8 + h] = a;
        }
    }
}

// QKV rows 4b..4b+3, 256 threads, no K-split (thread: col c, rows rg & rg+2).
__device__ __forceinline__ void body_qkv(const Params& P, int b, int t, SmemU& S) {
    int r0 = b * 4;
    int c = t & 127, rg = t >> 7;
    S.q.sx[rg][c]     = P.node[(r0 + rg) * DDIM + c];
    S.q.sx[rg + 2][c] = P.node[(r0 + rg + 2) * DDIM + c];
    __syncthreads();
    float aq0 = 0, ak0 = 0, av0 = 0, aq1 = 0, ak1 = 0, av1 = 0;
#pragma unroll 8
    for (int k = 0; k < DDIM; k++) {
        float wq = P.Wq[k * DDIM + c];
        float wk = P.Wk[k * DDIM + c];
        float wv = P.Wv[k * DDIM + c];
        float x0 = S.q.sx[rg][k];
        float x1 = S.q.sx[rg + 2][k];
        aq0 += x0 * wq; ak0 += x0 * wk; av0 += x0 * wv;
        aq1 += x1 * wq; ak1 += x1 * wk; av1 += x1 * wv;
    }
    float vbq = P.bq[c], vbk = P.bk[c], vbv = P.bv[c];
    P.Qf[(r0 + rg) * DDIM + c]     = (aq0 + vbq) * 0.25f;
    P.Kf[(r0 + rg) * DDIM + c]     = ak0 + vbk;
    P.Vf[(r0 + rg) * DDIM + c]     = av0 + vbv;
    P.Qf[(r0 + rg + 2) * DDIM + c] = (aq1 + vbq) * 0.25f;
    P.Kf[(r0 + rg + 2) * DDIM + c] = ak1 + vbk;
    P.Vf[(r0 + rg + 2) * DDIM + c] = av1 + vbv;
}

__device__ __forceinline__ void body_scatter(const Params& P, int g, bool is64) {
    if (g < NEDGE) {
        int s = is64 ? P.src[2 * g] : P.src[g];
        int d = is64 ? P.dst[2 * g] : P.dst[g];
        atomicMax(&P.eid[(long)s * NN + d], g);
        atomicOr(&P.bm[s * 64 + (d >> 5)], 1u << (d & 31));
        atomicOr(&P.bm[d * 64 + (s >> 5)], 1u << (s & 31));
    } else if (g < NEDGE + NN) {
        int i = g - NEDGE;
        atomicOr(&P.bm[i * 64 + (i >> 5)], 1u << (i & 31));
    }
}

// attention for row i, 256 threads (R12-proven body).
__device__ __forceinline__ void body_attn(const Params& P, int i, int t, SmemU& S) {
    if (t < 128) S.a.qrow[t] = P.Qf[i * DDIM + t];
    if (t < 64) {
        unsigned word = P.bm[i * 64 + t];
        int pc = __popc(word);
        int x = pc;
#pragma unroll
        for (int off = 1; off < 64; off <<= 1) {
            int y = __shfl_up(x, off);
            if (t >= off) x += y;
        }
        int cnt = __shfl(x, 63);
        if (cnt > CAP - 8) cnt = CAP - 8;
        int idx = x - pc;
        unsigned w = word;
        while (w && idx < CAP) {
            int bp = __ffs(w) - 1;
            S.a.lj[idx++] = (t << 5) + bp;
            w &= w - 1;
        }
        if (t < 8) S.a.lj[cnt + t] = 0;
        if (t == 0) S.a.scnt = cnt;
    }
    __syncthreads();
    int cnt = S.a.scnt;
    int cnt8 = (cnt + 7) & ~7;
    if (t < cnt8) S.a.lev[t] = (t < cnt) ? P.eid[(long)i * NN + S.a.lj[t]] : -1;
    __syncthreads();
    {
        int h = t & 7, nsl = t >> 3;
        const float4* q4 = (const float4*)(S.a.qrow + h * DHH);
        float4 q0 = q4[0], q1 = q4[1], q2 = q4[2], q3 = q4[3];
        for (int n = nsl; n < cnt8; n += 32) {
            int j = S.a.lj[n];
            const float4* k4 = (const float4*)(P.Kf + j * DDIM + h * DHH);
            float4 k0 = k4[0], k1 = k4[1], k2 = k4[2], k3 = k4[3];
            float s = q0.x * k0.x + q0.y * k0.y + q0.z * k0.z + q0.w * k0.w
                    + q1.x * k1.x + q1.y * k1.y + q1.z * k1.z + q1.w * k1.w
                    + q2.x * k2.x + q2.y * k2.y + q2.z * k2.z + q2.w * k2.w
                    + q3.x * k3.x + q3.y * k3.y + q3.z * k3.z + q3.w * k3.w;
            int ev = S.a.lev[n];
            if (ev >= 0) s += P.eb[ev * 8 + h];
            S.a.sc[n][h] = s;
        }
    }
    __syncthreads();
    {
        int hh = t >> 5, sub = t & 31;
        float m = -1e30f;
        for (int n = sub; n < cnt; n += 32) m = fmaxf(m, S.a.sc[n][hh]);
#pragma unroll
        for (int off = 1; off < 32; off <<= 1) m = fmaxf(m, __shfl_xor(m, off));
        float ssum = 0.f;
        for (int n = sub; n < cnt; n += 32) {
            float e = __expf(S.a.sc[n][hh] - m);
            S.a.sc[n][hh] = e;
            ssum += e;
        }
#pragma unroll
        for (int off = 1; off < 32; off <<= 1) ssum += __shfl_xor(ssum, off);
        if (sub == 0) S.a.hinv[hh] = 1.0f / ssum;
    }
    if (t < 64) {
        int p = cnt + (t >> 3);
        if (p < cnt8) S.a.sc[p][t & 7] = 0.f;
    }
    __syncthreads();
    {
        int g = t >> 7, c = t & 127, h2 = c >> 4;
        float a = 0.f;
#pragma unroll 4
        for (int n = g; n < cnt8; n += 2)
            a += S.a.sc[n][h2] * P.Vf[S.a.lj[n] * DDIM + c];
        S.a.redpv[g][c] = a;
    }
    __syncthreads();
    if (t < 128)
        P.attn_o[i * DDIM + t] = (S.a.redpv[0][t] + S.a.redpv[1][t]) * S.a.hinv[t >> 4];
}

// ===== cooperative: prep+QKV -> sync -> scatter -> sync -> attn. 2048x256 =====
__global__ __launch_bounds__(256, 8) void k_mega2(Params P) {
    __shared__ SmemU S;
    int b = blockIdx.x, t = threadIdx.x;
    int g = b * 256 + t;
    bool is64 = idx64(P.src);
    body_prep(P, g);
    if (b < 512) body_qkv(P, b, t, S);
    cg::this_grid().sync();
    body_scatter(P, g, is64);
    cg::this_grid().sync();
    body_attn(P, b, t, S);
}

// ===== fallbacks (plain, same bodies) =====
__global__ __launch_bounds__(256, 8) void k_pqf(Params P) {
    __shared__ SmemU S;
    int b = blockIdx.x, t = threadIdx.x;
    body_prep(P, b * 256 + t);
    if (b < 512) body_qkv(P, b, t, S);
}
__global__ __launch_bounds__(256) void k_scf(Params P) {
    body_scatter(P, blockIdx.x * 256 + threadIdx.x, idx64(P.src));
}
__global__ __launch_bounds__(256, 8) void k_atf(Params P) {
    __shared__ SmemU S;
    body_attn(P, blockIdx.x, threadIdx.x, S);
}

// ================= tail: Wo+LN1 -> FFN1 -> FFN2+LN2, ROWS=4 (R12-proven) =================
__global__ __launch_bounds__(512) void k_tail(float* out, const float* ain,
                                              fp_c Wo, fp_c bo, fp_c node, fp_c g1, fp_c b1,
                                              fp_c W1, fp_c bf1, fp_c W2, fp_c bf2,
                                              fp_c g2, fp_c b2) {
    __shared__ float sa[4][DDIM];
    __shared__ float red[4][4][DDIM];
    __shared__ float x1ld[4][DDIM];
    __shared__ float sh[4][FFN];
    __shared__ float2 sc2[8];
    int t = threadIdx.x;
    int r0 = blockIdx.x * 4;
    int c = t & 127;
    int ks = t >> 7;
    int rr = t >> 7, cc = t & 127;
    sa[rr][cc] = ain[r0 * DDIM + t];
    __syncthreads();
    {
        float acc[4] = {0, 0, 0, 0};
        int kbeg = ks * 32;
#pragma unroll 8
        for (int k = kbeg; k < kbeg + 32; k++) {
            float w = Wo[k * DDIM + c];
#pragma unroll
            for (int r = 0; r < 4; r++) acc[r] += sa[r][k] * w;
        }
#pragma unroll
        for (int r = 0; r < 4; r++) red[ks][r][c] = acc[r];
        __syncthreads();
        float val = red[0][rr][cc] + red[1][rr][cc] + red[2][rr][cc] + red[3][rr][cc];
        val += bo[cc] + node[(r0 + rr) * DDIM + cc];
        float vs = val, vq = val * val;
#pragma unroll
        for (int off = 32; off >= 1; off >>= 1) {
            vs += __shfl_down(vs, off);
            vq += __shfl_down(vq, off);
        }
        if ((t & 63) == 0) sc2[t >> 6] = make_float2(vs, vq);
        __syncthreads();
        float sum = sc2[2 * rr].x + sc2[2 * rr + 1].x;
        float sq  = sc2[2 * rr].y + sc2[2 * rr + 1].y;
        float mu = sum * (1.0f / DDIM);
        float var = sq * (1.0f / DDIM) - mu * mu;
        x1ld[rr][cc] = (val - mu) * rsqrtf(var + EPSV) * g1[cc] + b1[cc];
    }
    __syncthreads();
    {
        float acc[4] = {0, 0, 0, 0};
#pragma unroll 8
        for (int k = 0; k < DDIM; k++) {
            float w = W1[k * FFN + t];
#pragma unroll
            for (int r = 0; r < 4; r++) acc[r] += x1ld[r][k] * w;
        }
        float bb = bf1[t];
#pragma unroll
        for (int r = 0; r < 4; r++) sh[r][t] = fmaxf(acc[r] + bb, 0.f);
    }
    __syncthreads();
    {
        float acc[4] = {0, 0, 0, 0};
        int kbeg = ks * 128;
#pragma unroll 8
        for (int k = kbeg; k < kbeg + 128; k++) {
            float w = W2[k * DDIM + c];
#pragma unroll
            for (int r = 0; r < 4; r++) acc[r] += sh[r][k] * w;
        }
#pragma unroll
        for (int r = 0; r < 4; r++) red[ks][r][c] = acc[r];
        __syncthreads();
        float val = red[0][rr][cc] + red[1][rr][cc] + red[2][rr][cc] + red[3][rr][cc];
        val += bf2[cc] + x1ld[rr][cc];
        float vs = val, vq = val * val;
#pragma unroll
        for (int off = 32; off >= 1; off >>= 1) {
            vs += __shfl_down(vs, off);
            vq += __shfl_down(vq, off);
        }
        if ((t & 63) == 0) sc2[t >> 6] = make_float2(vs, vq);
        __syncthreads();
        float sum = sc2[2 * rr].x + sc2[2 * rr + 1].x;
        float sq  = sc2[2 * rr].y + sc2[2 * rr + 1].y;
        float mu = sum * (1.0f / DDIM);
        float var = sq * (1.0f / DDIM) - mu * mu;
        out[(r0 + rr) * DDIM + cc] = (val - mu) * rsqrtf(var + EPSV) * g2[cc] + b2[cc];
    }
}

extern "C" void kernel_launch(void* const* d_in, const int* in_sizes, int n_in,
                              void* d_out, int out_size, void* d_ws, size_t ws_size,
                              hipStream_t stream) {
    Params P;
    P.node      = (const float*)d_in[0];
    P.edge_feat = (const float*)d_in[1];
    P.src = (const int*)d_in[2];
    P.dst = (const int*)d_in[3];
    P.Wq = (const float*)d_in[4];   P.bq = (const float*)d_in[5];
    P.Wk = (const float*)d_in[6];   P.bk = (const float*)d_in[7];
    P.Wv = (const float*)d_in[8];   P.bv = (const float*)d_in[9];
    P.Wo = (const float*)d_in[10];  P.bo = (const float*)d_in[11];
    P.We = (const float*)d_in[12];  P.be = (const float*)d_in[13];
    fp_c g1 = (fp_c)d_in[14], b1n = (fp_c)d_in[15];
    fp_c g2 = (fp_c)d_in[16], b2n = (fp_c)d_in[17];
    fp_c W1 = (fp_c)d_in[18], bf1 = (fp_c)d_in[19];
    fp_c W2 = (fp_c)d_in[20], bf2 = (fp_c)d_in[21];

    char* ws = (char*)d_ws;
    P.eid    = (int*)ws;      ws += (size_t)NN * NN * 4;     // 16.8 MB
    P.bm     = (unsigned*)ws; ws += (size_t)NN * 64 * 4;     // 512 KB
    P.eb     = (float*)ws;    ws += (size_t)NEDGE * 8 * 4;   // 2 MB
    P.Qf     = (float*)ws;    ws += (size_t)NN * DDIM * 4;
    P.Kf     = (float*)ws;    ws += (size_t)NN * DDIM * 4;
    P.Vf     = (float*)ws;    ws += (size_t)NN * DDIM * 4;
    P.attn_o = (float*)ws;    ws += (size_t)NN * DDIM * 4;

    int dev = 0;
    hipGetDevice(&dev);
    int coop = 0;
    hipDeviceGetAttribute(&coop, hipDeviceAttributeCooperativeLaunch, dev);

    bool done = false;
    if (coop) {
        void* args[] = { &P };
        hipError_t e = hipLaunchCooperativeKernel(reinterpret_cast<void*>(k_mega2),
                                                  dim3(NN), dim3(256), args, 0, stream);
        done = (e == hipSuccess);
    }
    if (!done) {
        k_pqf<<<NN, 256, 0, stream>>>(P);
        k_scf<<<(NEDGE + NN + 255) / 256, 256, 0, stream>>>(P);
        k_atf<<<NN, 256, 0, stream>>>(P);
    }
    k_tail<<<NN / 4, 512, 0, stream>>>((float*)d_out, P.attn_o, P.Wo, P.bo, P.node,
                                       g1, b1n, W1, bf1, W2, bf2, g2, b2n);
}